// Round 1
// baseline (1174.362 us; speedup 1.0000x reference)
//
#include <hip/hip_runtime.h>

// GNN_2911987826770: 6x GraphConv(add)+BN(train)+ReLU, mean-pool, linear.
// Strategy: CSR-by-dst built once; per layer ONE bf16 MFMA GEMM
//   H[20000,512] = A[20000,1024](bf16) @ Wt[512,1024]^T(bf16) + b_rel
// where A = [agg | x] and Wt = [W_rel; W_root]^T (pre-converted).
// BN stats (sum/sumsq) column-reduced in f32, normalize+ReLU writes bf16 x
// back into A's second half for the next layer's gather+GEMM.

typedef unsigned short u16;
typedef unsigned int u32;
typedef __attribute__((ext_vector_type(8))) short bf16x8;   // 8 bf16 = 4 VGPRs
typedef __attribute__((ext_vector_type(4))) float f32x4;

#define DFEAT 512
#define KDIM 1024
#define NLAYER 6
#define NGRAPH 64
#define NCLS 10
#define BN_EPS 1e-5f

__device__ __forceinline__ float bf_lo(u32 u) { union { u32 i; float f; } v; v.i = u << 16; return v.f; }
__device__ __forceinline__ float bf_hi(u32 u) { union { u32 i; float f; } v; v.i = u & 0xFFFF0000u; return v.f; }
__device__ __forceinline__ u16 f2bf(float f) {           // round-to-nearest-even
  union { float f; u32 i; } v; v.f = f;
  u32 r = v.i + 0x7FFFu + ((v.i >> 16) & 1u);
  return (u16)(r >> 16);
}
__device__ __forceinline__ u32 pack2(float lo, float hi) {
  return (u32)f2bf(lo) | ((u32)f2bf(hi) << 16);
}

// ---------------- CSR build ----------------
__global__ void hist_kernel(const int* __restrict__ ei, int* __restrict__ counts, int E) {
  int e = blockIdx.x * 256 + threadIdx.x;
  if (e < E) atomicAdd(&counts[ei[E + e]], 1);   // row 1 of edge_index = dst
}

__global__ __launch_bounds__(1024) void scan_kernel(const int* __restrict__ counts,
                                                    int* __restrict__ row_ptr, int n) {
  __shared__ int buf[1024];
  int tid = threadIdx.x;
  int carry = 0;
  for (int base = 0; base < n; base += 1024) {
    int i = base + tid;
    int v = (i < n) ? counts[i] : 0;
    buf[tid] = v;
    __syncthreads();
    int x = v;
    for (int off = 1; off < 1024; off <<= 1) {
      int t = (tid >= off) ? buf[tid - off] : 0;
      __syncthreads();
      x += t;
      buf[tid] = x;
      __syncthreads();
    }
    if (i < n) row_ptr[i] = carry + x - v;      // exclusive scan
    int tot = buf[1023];
    __syncthreads();
    carry += tot;
  }
  if (tid == 0) row_ptr[n] = carry;
}

__global__ void scatter_kernel(const int* __restrict__ ei, int* __restrict__ cursor,
                               int* __restrict__ csr_src, int E) {
  int e = blockIdx.x * 256 + threadIdx.x;
  if (e < E) {
    int d = ei[E + e];
    int pos = atomicAdd(&cursor[d], 1);
    csr_src[pos] = ei[e];                        // row 0 = src
  }
}

// ---------------- weight / input conversion ----------------
// Wt[l][n][k] = bf16( k<512 ? W_rel[l][k][n] : W_root[l][k-512][n] )
__global__ void wconv_kernel(const float* __restrict__ Wrel, const float* __restrict__ Wroot,
                             u16* __restrict__ Wt) {
  int idx = blockIdx.x * 256 + threadIdx.x;      // 6*512*1024 total, k fastest
  int k = idx & 1023;
  int n = (idx >> 10) & 511;
  int l = idx >> 19;
  float v = (k < DFEAT) ? Wrel[((size_t)l * DFEAT + k) * DFEAT + n]
                        : Wroot[((size_t)l * DFEAT + (k - DFEAT)) * DFEAT + n];
  Wt[idx] = f2bf(v);
}

// x f32 -> bf16 into A[:,512:1024]
__global__ void xconv_kernel(const float* __restrict__ x, u16* __restrict__ A, int M) {
  int idx = blockIdx.x * 256 + threadIdx.x;      // each thread: 4 cols
  int row = idx >> 7;
  int c4 = (idx & 127) * 4;
  if (row >= M) return;
  float4 v = *(const float4*)&x[(size_t)row * DFEAT + c4];
  u32 p0 = pack2(v.x, v.y), p1 = pack2(v.z, v.w);
  uint2 o; o.x = p0; o.y = p1;
  *(uint2*)&A[(size_t)row * KDIM + DFEAT + c4] = o;
}

// ---------------- gather (segment_sum by dst) ----------------
// wave per dst node; lane holds 8 cols (16B loads). Reads A x-part, writes agg part.
__global__ __launch_bounds__(256) void gather_kernel(u16* __restrict__ A,
                                                     const int* __restrict__ row_ptr,
                                                     const int* __restrict__ csr_src, int n) {
  int dst = blockIdx.x * 4 + (threadIdx.x >> 6);
  if (dst >= n) return;
  int lane = threadIdx.x & 63;
  int beg = row_ptr[dst], end = row_ptr[dst + 1];
  float a0 = 0, a1 = 0, a2 = 0, a3 = 0, a4 = 0, a5 = 0, a6 = 0, a7 = 0;
  for (int e = beg; e < end; ++e) {
    int s = csr_src[e];
    uint4 v = *(const uint4*)&A[(size_t)s * KDIM + DFEAT + lane * 8];
    a0 += bf_lo(v.x); a1 += bf_hi(v.x);
    a2 += bf_lo(v.y); a3 += bf_hi(v.y);
    a4 += bf_lo(v.z); a5 += bf_hi(v.z);
    a6 += bf_lo(v.w); a7 += bf_hi(v.w);
  }
  uint4 o;
  o.x = pack2(a0, a1); o.y = pack2(a2, a3); o.z = pack2(a4, a5); o.w = pack2(a6, a7);
  *(uint4*)&A[(size_t)dst * KDIM + lane * 8] = o;
}

// ---------------- GEMM: H = A(bf16) @ Wt^T(bf16) + bias ----------------
// 128x128 tile, 4 waves (2x2), each wave 64x64 via 4x4 of mfma 16x16x32.
#define BM 128
#define BN 128
#define BK 32
__global__ __launch_bounds__(256, 2) void gemm_kernel(const u16* __restrict__ A,
                                                      const u16* __restrict__ Bt,
                                                      const float* __restrict__ bias,
                                                      float* __restrict__ H, int M) {
  __shared__ u16 As[BM * BK];   // 8 KB
  __shared__ u16 Bs[BN * BK];   // 8 KB
  const int tid = threadIdx.x;
  const int wid = tid >> 6, lane = tid & 63;
  const int wm = wid >> 1, wn = wid & 1;
  const int l16 = lane & 15, quad = lane >> 4;
  const int m0 = blockIdx.x * BM;
  const int n0 = blockIdx.y * BN;

  const int srow = tid >> 2;
  const int scol = (tid & 3) * 8;
  int ar0 = m0 + srow;      if (ar0 >= M) ar0 = M - 1;   // clamp: stores are masked
  int ar1 = m0 + 64 + srow; if (ar1 >= M) ar1 = M - 1;
  const int br0 = n0 + srow, br1 = n0 + 64 + srow;       // 512 rows: always valid

  f32x4 acc[4][4] = {};

  for (int k0 = 0; k0 < KDIM; k0 += BK) {
    uint4 ga0 = *(const uint4*)&A[(size_t)ar0 * KDIM + k0 + scol];
    uint4 ga1 = *(const uint4*)&A[(size_t)ar1 * KDIM + k0 + scol];
    uint4 gb0 = *(const uint4*)&Bt[(size_t)br0 * KDIM + k0 + scol];
    uint4 gb1 = *(const uint4*)&Bt[(size_t)br1 * KDIM + k0 + scol];
    __syncthreads();
    *(uint4*)&As[srow * BK + scol] = ga0;
    *(uint4*)&As[(64 + srow) * BK + scol] = ga1;
    *(uint4*)&Bs[srow * BK + scol] = gb0;
    *(uint4*)&Bs[(64 + srow) * BK + scol] = gb1;
    __syncthreads();
    bf16x8 af[4], bfr[4];
#pragma unroll
    for (int i = 0; i < 4; i++) {
      af[i]  = *(const bf16x8*)&As[(wm * 64 + i * 16 + l16) * BK + quad * 8];
      bfr[i] = *(const bf16x8*)&Bs[(wn * 64 + i * 16 + l16) * BK + quad * 8];
    }
#pragma unroll
    for (int i = 0; i < 4; i++)
#pragma unroll
      for (int j = 0; j < 4; j++)
        acc[i][j] = __builtin_amdgcn_mfma_f32_16x16x32_bf16(af[i], bfr[j], acc[i][j], 0, 0, 0);
  }

  // epilogue: D row = quad*4+reg (A's m), col = lane&15 (B's n)
#pragma unroll
  for (int j = 0; j < 4; j++) {
    int col = n0 + wn * 64 + j * 16 + l16;
    float bv = bias[col];
#pragma unroll
    for (int i = 0; i < 4; i++) {
      int rbase = m0 + wm * 64 + i * 16 + quad * 4;
#pragma unroll
      for (int r = 0; r < 4; r++) {
        int row = rbase + r;
        if (row < M) H[(size_t)row * DFEAT + col] = acc[i][j][r] + bv;
      }
    }
  }
}

// ---------------- BN stats / finalize / normalize ----------------
__global__ __launch_bounds__(512) void stats_kernel(const float* __restrict__ H,
                                                    float* __restrict__ sums, int M) {
  int col = threadIdx.x;
  float s = 0.f, s2 = 0.f;
  for (int r = blockIdx.x; r < M; r += gridDim.x) {
    float v = H[(size_t)r * DFEAT + col];
    s += v; s2 += v * v;
  }
  atomicAdd(&sums[col], s);
  atomicAdd(&sums[DFEAT + col], s2);
}

__global__ void finalize_kernel(const float* __restrict__ sums, const float* __restrict__ gamma,
                                const float* __restrict__ beta, float* __restrict__ ss, float invN) {
  int c = threadIdx.x;
  float mu = sums[c] * invN;
  float var = sums[DFEAT + c] * invN - mu * mu;
  float sc = gamma[c] * rsqrtf(var + BN_EPS);
  ss[c] = sc;
  ss[DFEAT + c] = beta[c] - mu * sc;
}

__global__ void norm_kernel(const float* __restrict__ H, const float* __restrict__ ss,
                            u16* __restrict__ A, int M) {
  int idx = blockIdx.x * 256 + threadIdx.x;      // 4 cols per thread
  int row = idx >> 7;
  int c4 = (idx & 127) * 4;
  if (row >= M) return;
  float4 h = *(const float4*)&H[(size_t)row * DFEAT + c4];
  float x0 = fmaxf(h.x * ss[c4 + 0] + ss[DFEAT + c4 + 0], 0.f);
  float x1 = fmaxf(h.y * ss[c4 + 1] + ss[DFEAT + c4 + 1], 0.f);
  float x2 = fmaxf(h.z * ss[c4 + 2] + ss[DFEAT + c4 + 2], 0.f);
  float x3 = fmaxf(h.w * ss[c4 + 3] + ss[DFEAT + c4 + 3], 0.f);
  uint2 o; o.x = pack2(x0, x1); o.y = pack2(x2, x3);
  *(uint2*)&A[(size_t)row * KDIM + DFEAT + c4] = o;
}

// ---------------- pooling + classifier ----------------
__device__ __forceinline__ int lower_bound_dev(const int* a, int n, int v) {
  int lo = 0, hi = n;
  while (lo < hi) { int mid = (lo + hi) >> 1; if (a[mid] < v) lo = mid + 1; else hi = mid; }
  return lo;
}

__global__ __launch_bounds__(512) void pool_kernel(const u16* __restrict__ A,
                                                   const int* __restrict__ batch,
                                                   float* __restrict__ pooled, int n) {
  int g = blockIdx.x;
  int lo = lower_bound_dev(batch, n, g);
  int hi = lower_bound_dev(batch, n, g + 1);
  int col = threadIdx.x;
  float s = 0.f;
  for (int r = lo; r < hi; ++r) {
    u16 u = A[(size_t)r * KDIM + DFEAT + col];
    union { u32 i; float f; } v; v.i = ((u32)u) << 16;
    s += v.f;
  }
  float cnt = (float)(hi - lo);
  pooled[g * DFEAT + col] = s / fmaxf(cnt, 1.0f);
}

__global__ void final_kernel(const float* __restrict__ pooled, const float* __restrict__ lin_w,
                             const float* __restrict__ lin_b, float* __restrict__ out) {
  int t = blockIdx.x * 64 + threadIdx.x;
  if (t >= NGRAPH * NCLS) return;
  int g = t / NCLS, c = t % NCLS;
  float s = lin_b[c];
  for (int k = 0; k < DFEAT; ++k) s += pooled[g * DFEAT + k] * lin_w[k * NCLS + c];
  out[t] = s;
}

// ---------------- orchestration ----------------
extern "C" void kernel_launch(void* const* d_in, const int* in_sizes, int n_in,
                              void* d_out, int out_size, void* d_ws, size_t ws_size,
                              hipStream_t stream) {
  const float* x      = (const float*)d_in[0];
  const int*   ei     = (const int*)d_in[1];
  const int*   batch  = (const int*)d_in[2];
  const float* W_rel  = (const float*)d_in[3];
  const float* b_rel  = (const float*)d_in[4];
  const float* W_root = (const float*)d_in[5];
  const float* gamma  = (const float*)d_in[6];
  const float* beta   = (const float*)d_in[7];
  const float* lin_w  = (const float*)d_in[8];
  const float* lin_b  = (const float*)d_in[9];
  float* out = (float*)d_out;

  const int N = in_sizes[0] / DFEAT;    // 20000
  const int E = in_sizes[1] / 2;        // 320000

  char* p = (char*)d_ws;
  u16*   A       = (u16*)p;    p += (size_t)N * KDIM * 2;          // 40.96 MB
  float* H       = (float*)p;  p += (size_t)N * DFEAT * 4;         // 40.96 MB
  u16*   Wt      = (u16*)p;    p += (size_t)NLAYER * DFEAT * KDIM * 2; // 6.29 MB
  int*   row_ptr = (int*)p;    p += ((size_t)(N + 1) * 4 + 15) / 16 * 16;
  int*   cursor  = (int*)p;    p += (size_t)N * 4;                 // doubles as counts
  int*   csr_src = (int*)p;    p += (size_t)E * 4;
  float* sums    = (float*)p;  p += 2 * DFEAT * 4;
  float* ss      = (float*)p;  p += 2 * DFEAT * 4;
  float* pooled  = (float*)p;  p += (size_t)NGRAPH * DFEAT * 4;

  // ---- CSR build (edge structure shared by all 6 layers) ----
  hipMemsetAsync(cursor, 0, (size_t)N * 4, stream);
  hist_kernel<<<(E + 255) / 256, 256, 0, stream>>>(ei, cursor, E);
  scan_kernel<<<1, 1024, 0, stream>>>(cursor, row_ptr, N);
  hipMemcpyAsync(cursor, row_ptr, (size_t)N * 4, hipMemcpyDeviceToDevice, stream);
  scatter_kernel<<<(E + 255) / 256, 256, 0, stream>>>(ei, cursor, csr_src, E);

  // ---- weight + input conversion to bf16 ----
  wconv_kernel<<<(NLAYER * DFEAT * KDIM) / 256, 256, 0, stream>>>(W_rel, W_root, Wt);
  xconv_kernel<<<(N * 128 + 255) / 256, 256, 0, stream>>>(x, A, N);

  const int gemm_gx = (N + BM - 1) / BM;   // 157
  dim3 gemm_grid(gemm_gx, DFEAT / BN, 1);  // (157, 4)

  for (int l = 0; l < NLAYER; ++l) {
    gather_kernel<<<(N + 3) / 4, 256, 0, stream>>>(A, row_ptr, csr_src, N);
    gemm_kernel<<<gemm_grid, 256, 0, stream>>>(A, Wt + (size_t)l * DFEAT * KDIM,
                                               b_rel + (size_t)l * DFEAT, H, N);
    hipMemsetAsync(sums, 0, 2 * DFEAT * 4, stream);
    stats_kernel<<<160, 512, 0, stream>>>(H, sums, N);
    finalize_kernel<<<1, DFEAT, 0, stream>>>(sums, gamma + (size_t)l * DFEAT,
                                             beta + (size_t)l * DFEAT, ss, 1.0f / (float)N);
    norm_kernel<<<(N * 128 + 255) / 256, 256, 0, stream>>>(H, ss, A, N);
  }

  pool_kernel<<<NGRAPH, DFEAT, 0, stream>>>(A, batch, pooled, N);
  final_kernel<<<(NGRAPH * NCLS + 63) / 64, 64, 0, stream>>>(pooled, lin_w, lin_b, out);
}

// Round 2
// 819.684 us; speedup vs baseline: 1.4327x; 1.4327x over previous
//
#include <hip/hip_runtime.h>

// GNN_2911987826770: 6x GraphConv(add)+BN(train)+ReLU, mean-pool, linear.
// CSR-by-dst built once; per layer ONE bf16 MFMA GEMM
//   H[20000,512] = A[20000,1024](bf16) @ Wt[512,1024]^T(bf16) + b_rel
// with A = [agg | x], Wt = [W_rel; W_root]^T. BN stats fused into GEMM
// epilogue (shfl + LDS + atomics); normalize+ReLU writes bf16 x back into A.
// R2: global_load_lds(16B) GEMM staging, parallel pool, stats fusion.

typedef unsigned short u16;
typedef unsigned int u32;
typedef __attribute__((ext_vector_type(8))) short bf16x8;   // 8 bf16 = 4 VGPRs
typedef __attribute__((ext_vector_type(4))) float f32x4;

#define DFEAT 512
#define KDIM 1024
#define NLAYER 6
#define NGRAPH 64
#define NCLS 10
#define BN_EPS 1e-5f

__device__ __forceinline__ float bf_lo(u32 u) { union { u32 i; float f; } v; v.i = u << 16; return v.f; }
__device__ __forceinline__ float bf_hi(u32 u) { union { u32 i; float f; } v; v.i = u & 0xFFFF0000u; return v.f; }
__device__ __forceinline__ u16 f2bf(float f) {           // round-to-nearest-even
  union { float f; u32 i; } v; v.f = f;
  u32 r = v.i + 0x7FFFu + ((v.i >> 16) & 1u);
  return (u16)(r >> 16);
}
__device__ __forceinline__ u32 pack2(float lo, float hi) {
  return (u32)f2bf(lo) | ((u32)f2bf(hi) << 16);
}

// async global->LDS, 16B per lane. LDS dest is wave-uniform base + lane*16.
__device__ __forceinline__ void gload_lds16(const u16* g, u16* lds_base) {
  __builtin_amdgcn_global_load_lds(
      (const __attribute__((address_space(1))) u32*)g,
      (__attribute__((address_space(3))) u32*)lds_base, 16, 0, 0);
}

// ---------------- CSR build ----------------
__global__ void hist_kernel(const int* __restrict__ ei, int* __restrict__ counts, int E) {
  int e = blockIdx.x * 256 + threadIdx.x;
  if (e < E) atomicAdd(&counts[ei[E + e]], 1);   // row 1 of edge_index = dst
}

__global__ __launch_bounds__(1024) void scan_kernel(const int* __restrict__ counts,
                                                    int* __restrict__ row_ptr, int n) {
  __shared__ int buf[1024];
  int tid = threadIdx.x;
  int carry = 0;
  for (int base = 0; base < n; base += 1024) {
    int i = base + tid;
    int v = (i < n) ? counts[i] : 0;
    buf[tid] = v;
    __syncthreads();
    int x = v;
    for (int off = 1; off < 1024; off <<= 1) {
      int t = (tid >= off) ? buf[tid - off] : 0;
      __syncthreads();
      x += t;
      buf[tid] = x;
      __syncthreads();
    }
    if (i < n) row_ptr[i] = carry + x - v;      // exclusive scan
    int tot = buf[1023];
    __syncthreads();
    carry += tot;
  }
  if (tid == 0) row_ptr[n] = carry;
}

__global__ void scatter_kernel(const int* __restrict__ ei, int* __restrict__ cursor,
                               int* __restrict__ csr_src, int E) {
  int e = blockIdx.x * 256 + threadIdx.x;
  if (e < E) {
    int d = ei[E + e];
    int pos = atomicAdd(&cursor[d], 1);
    csr_src[pos] = ei[e];                        // row 0 = src
  }
}

// ---------------- weight / input conversion ----------------
__global__ void wconv_kernel(const float* __restrict__ Wrel, const float* __restrict__ Wroot,
                             u16* __restrict__ Wt) {
  int idx = blockIdx.x * 256 + threadIdx.x;      // 6*512*1024 total, k fastest
  int k = idx & 1023;
  int n = (idx >> 10) & 511;
  int l = idx >> 19;
  float v = (k < DFEAT) ? Wrel[((size_t)l * DFEAT + k) * DFEAT + n]
                        : Wroot[((size_t)l * DFEAT + (k - DFEAT)) * DFEAT + n];
  Wt[idx] = f2bf(v);
}

__global__ void xconv_kernel(const float* __restrict__ x, u16* __restrict__ A, int M) {
  int idx = blockIdx.x * 256 + threadIdx.x;      // each thread: 4 cols
  int row = idx >> 7;
  int c4 = (idx & 127) * 4;
  if (row >= M) return;
  float4 v = *(const float4*)&x[(size_t)row * DFEAT + c4];
  uint2 o; o.x = pack2(v.x, v.y); o.y = pack2(v.z, v.w);
  *(uint2*)&A[(size_t)row * KDIM + DFEAT + c4] = o;
}

// ---------------- gather (segment_sum by dst) ----------------
__global__ __launch_bounds__(256) void gather_kernel(u16* __restrict__ A,
                                                     const int* __restrict__ row_ptr,
                                                     const int* __restrict__ csr_src, int n) {
  int dst = blockIdx.x * 4 + (threadIdx.x >> 6);
  if (dst >= n) return;
  int lane = threadIdx.x & 63;
  int beg = row_ptr[dst], end = row_ptr[dst + 1];
  float a0 = 0, a1 = 0, a2 = 0, a3 = 0, a4 = 0, a5 = 0, a6 = 0, a7 = 0;
  int e = beg;
  for (; e + 1 < end; e += 2) {                  // 2-wide: two loads in flight
    int s0 = csr_src[e], s1 = csr_src[e + 1];
    uint4 v0 = *(const uint4*)&A[(size_t)s0 * KDIM + DFEAT + lane * 8];
    uint4 v1 = *(const uint4*)&A[(size_t)s1 * KDIM + DFEAT + lane * 8];
    a0 += bf_lo(v0.x) + bf_lo(v1.x); a1 += bf_hi(v0.x) + bf_hi(v1.x);
    a2 += bf_lo(v0.y) + bf_lo(v1.y); a3 += bf_hi(v0.y) + bf_hi(v1.y);
    a4 += bf_lo(v0.z) + bf_lo(v1.z); a5 += bf_hi(v0.z) + bf_hi(v1.z);
    a6 += bf_lo(v0.w) + bf_lo(v1.w); a7 += bf_hi(v0.w) + bf_hi(v1.w);
  }
  if (e < end) {
    int s = csr_src[e];
    uint4 v = *(const uint4*)&A[(size_t)s * KDIM + DFEAT + lane * 8];
    a0 += bf_lo(v.x); a1 += bf_hi(v.x);
    a2 += bf_lo(v.y); a3 += bf_hi(v.y);
    a4 += bf_lo(v.z); a5 += bf_hi(v.z);
    a6 += bf_lo(v.w); a7 += bf_hi(v.w);
  }
  uint4 o;
  o.x = pack2(a0, a1); o.y = pack2(a2, a3); o.z = pack2(a4, a5); o.w = pack2(a6, a7);
  *(uint4*)&A[(size_t)dst * KDIM + lane * 8] = o;
}

// ---------------- GEMM: H = A(bf16) @ Wt^T(bf16) + bias, + BN stats ----------------
#define BM 128
#define BN 128
#define BK 32
__global__ __launch_bounds__(256, 2) void gemm_kernel(const u16* __restrict__ A,
                                                      const u16* __restrict__ Bt,
                                                      const float* __restrict__ bias,
                                                      float* __restrict__ H,
                                                      float* __restrict__ sums, int M) {
  __shared__ u16 As[BM * BK];     // 8 KB
  __shared__ u16 Bs[BN * BK];     // 8 KB
  __shared__ float sred[2 * BN];  // 1 KB: col sums / sumsq
  const int tid = threadIdx.x;
  const int wid = tid >> 6, lane = tid & 63;
  const int wm = wid >> 1, wn = wid & 1;
  const int l16 = lane & 15, quad = lane >> 4;
  const int m0 = blockIdx.x * BM;
  const int n0 = blockIdx.y * BN;

  if (tid < 2 * BN) sred[tid] = 0.f;

  // staging geometry: wave wid stages 16 rows per instruction, lane -> (row=lane>>2, kc=(lane&3)*8)
  const int lrow = lane >> 2;
  const int kc = (lane & 3) * 8;
  int ar0 = m0 + wid * 16 + lrow;       if (ar0 >= M) ar0 = M - 1;   // clamp, stores masked
  int ar1 = m0 + 64 + wid * 16 + lrow;  if (ar1 >= M) ar1 = M - 1;
  const int br0 = n0 + wid * 16 + lrow;
  const int br1 = n0 + 64 + wid * 16 + lrow;
  u16* lA0 = &As[(wid * 16) * BK];
  u16* lA1 = &As[(64 + wid * 16) * BK];
  u16* lB0 = &Bs[(wid * 16) * BK];
  u16* lB1 = &Bs[(64 + wid * 16) * BK];

  f32x4 acc[4][4] = {};

  for (int k0 = 0; k0 < KDIM; k0 += BK) {
    __syncthreads();   // previous iter's ds_reads done before DMA overwrite
    gload_lds16(&A[(size_t)ar0 * KDIM + k0 + kc], lA0);
    gload_lds16(&A[(size_t)ar1 * KDIM + k0 + kc], lA1);
    gload_lds16(&Bt[(size_t)br0 * KDIM + k0 + kc], lB0);
    gload_lds16(&Bt[(size_t)br1 * KDIM + k0 + kc], lB1);
    __syncthreads();   // vmcnt(0) drain: LDS tile visible
    bf16x8 af[4], bfr[4];
#pragma unroll
    for (int i = 0; i < 4; i++) {
      af[i]  = *(const bf16x8*)&As[(wm * 64 + i * 16 + l16) * BK + quad * 8];
      bfr[i] = *(const bf16x8*)&Bs[(wn * 64 + i * 16 + l16) * BK + quad * 8];
    }
#pragma unroll
    for (int i = 0; i < 4; i++)
#pragma unroll
      for (int j = 0; j < 4; j++)
        acc[i][j] = __builtin_amdgcn_mfma_f32_16x16x32_bf16(af[i], bfr[j], acc[i][j], 0, 0, 0);
  }

  // epilogue: D row = quad*4+reg, col = l16. Store H + per-column BN partials.
#pragma unroll
  for (int j = 0; j < 4; j++) {
    int col = n0 + wn * 64 + j * 16 + l16;
    float bv = bias[col];
    float s = 0.f, s2 = 0.f;
#pragma unroll
    for (int i = 0; i < 4; i++) {
      int rbase = m0 + wm * 64 + i * 16 + quad * 4;
#pragma unroll
      for (int r = 0; r < 4; r++) {
        int row = rbase + r;
        if (row < M) {
          float v = acc[i][j][r] + bv;
          H[(size_t)row * DFEAT + col] = v;
          s += v; s2 += v * v;
        }
      }
    }
    // reduce across the 4 quads (lanes l16, +16, +32, +48 share col)
    s  += __shfl_xor(s, 16);  s  += __shfl_xor(s, 32);
    s2 += __shfl_xor(s2, 16); s2 += __shfl_xor(s2, 32);
    if (quad == 0) {
      int cl = wn * 64 + j * 16 + l16;
      atomicAdd(&sred[cl], s);
      atomicAdd(&sred[BN + cl], s2);
    }
  }
  __syncthreads();
  if (tid < BN) {
    atomicAdd(&sums[n0 + tid], sred[tid]);
    atomicAdd(&sums[DFEAT + n0 + tid], sred[BN + tid]);
  }
}

// ---------------- BN finalize / normalize ----------------
__global__ void finalize_kernel(const float* __restrict__ sums, const float* __restrict__ gamma,
                                const float* __restrict__ beta, float* __restrict__ ss, float invN) {
  int c = threadIdx.x;
  float mu = sums[c] * invN;
  float var = sums[DFEAT + c] * invN - mu * mu;
  float sc = gamma[c] * rsqrtf(var + BN_EPS);
  ss[c] = sc;
  ss[DFEAT + c] = beta[c] - mu * sc;
}

__global__ void norm_kernel(const float* __restrict__ H, const float* __restrict__ ss,
                            u16* __restrict__ A, int M) {
  int idx = blockIdx.x * 256 + threadIdx.x;      // 4 cols per thread
  int row = idx >> 7;
  int c4 = (idx & 127) * 4;
  if (row >= M) return;
  float4 h = *(const float4*)&H[(size_t)row * DFEAT + c4];
  float x0 = fmaxf(h.x * ss[c4 + 0] + ss[DFEAT + c4 + 0], 0.f);
  float x1 = fmaxf(h.y * ss[c4 + 1] + ss[DFEAT + c4 + 1], 0.f);
  float x2 = fmaxf(h.z * ss[c4 + 2] + ss[DFEAT + c4 + 2], 0.f);
  float x3 = fmaxf(h.w * ss[c4 + 3] + ss[DFEAT + c4 + 3], 0.f);
  uint2 o; o.x = pack2(x0, x1); o.y = pack2(x2, x3);
  *(uint2*)&A[(size_t)row * KDIM + DFEAT + c4] = o;
}

// ---------------- pooling + classifier ----------------
__device__ __forceinline__ int lower_bound_dev(const int* a, int n, int v) {
  int lo = 0, hi = n;
  while (lo < hi) { int mid = (lo + hi) >> 1; if (a[mid] < v) lo = mid + 1; else hi = mid; }
  return lo;
}

// block per graph: 1024 threads = 16 row-streams x 64 lanes (8 cols each)
__global__ __launch_bounds__(1024) void pool_kernel(const u16* __restrict__ A,
                                                    const int* __restrict__ batch,
                                                    float* __restrict__ pooled, int n) {
  __shared__ float red[DFEAT];
  int g = blockIdx.x;
  int tid = threadIdx.x;
  if (tid < DFEAT) red[tid] = 0.f;
  int lo = lower_bound_dev(batch, n, g);
  int hi = lower_bound_dev(batch, n, g + 1);
  int rowOff = tid >> 6, lane = tid & 63;
  float a0 = 0, a1 = 0, a2 = 0, a3 = 0, a4 = 0, a5 = 0, a6 = 0, a7 = 0;
  for (int r = lo + rowOff; r < hi; r += 16) {
    uint4 v = *(const uint4*)&A[(size_t)r * KDIM + DFEAT + lane * 8];
    a0 += bf_lo(v.x); a1 += bf_hi(v.x);
    a2 += bf_lo(v.y); a3 += bf_hi(v.y);
    a4 += bf_lo(v.z); a5 += bf_hi(v.z);
    a6 += bf_lo(v.w); a7 += bf_hi(v.w);
  }
  __syncthreads();
  int c0 = lane * 8;
  atomicAdd(&red[c0 + 0], a0); atomicAdd(&red[c0 + 1], a1);
  atomicAdd(&red[c0 + 2], a2); atomicAdd(&red[c0 + 3], a3);
  atomicAdd(&red[c0 + 4], a4); atomicAdd(&red[c0 + 5], a5);
  atomicAdd(&red[c0 + 6], a6); atomicAdd(&red[c0 + 7], a7);
  __syncthreads();
  if (tid < DFEAT) pooled[g * DFEAT + tid] = red[tid] / fmaxf((float)(hi - lo), 1.0f);
}

// wave per graph
__global__ __launch_bounds__(64) void final_kernel(const float* __restrict__ pooled,
                                                   const float* __restrict__ lin_w,
                                                   const float* __restrict__ lin_b,
                                                   float* __restrict__ out) {
  int g = blockIdx.x;
  int lane = threadIdx.x;
  float acc[NCLS] = {};
  float4 p0 = *(const float4*)&pooled[g * DFEAT + lane * 8];
  float4 p1 = *(const float4*)&pooled[g * DFEAT + lane * 8 + 4];
  float pv[8] = {p0.x, p0.y, p0.z, p0.w, p1.x, p1.y, p1.z, p1.w};
#pragma unroll
  for (int j = 0; j < 8; j++) {
    int k = lane * 8 + j;
#pragma unroll
    for (int c = 0; c < NCLS; c++) acc[c] += pv[j] * lin_w[k * NCLS + c];
  }
#pragma unroll
  for (int off = 32; off > 0; off >>= 1)
#pragma unroll
    for (int c = 0; c < NCLS; c++) acc[c] += __shfl_down(acc[c], off);
  if (lane == 0)
#pragma unroll
    for (int c = 0; c < NCLS; c++) out[g * NCLS + c] = acc[c] + lin_b[c];
}

// ---------------- orchestration ----------------
extern "C" void kernel_launch(void* const* d_in, const int* in_sizes, int n_in,
                              void* d_out, int out_size, void* d_ws, size_t ws_size,
                              hipStream_t stream) {
  const float* x      = (const float*)d_in[0];
  const int*   ei     = (const int*)d_in[1];
  const int*   batch  = (const int*)d_in[2];
  const float* W_rel  = (const float*)d_in[3];
  const float* b_rel  = (const float*)d_in[4];
  const float* W_root = (const float*)d_in[5];
  const float* gamma  = (const float*)d_in[6];
  const float* beta   = (const float*)d_in[7];
  const float* lin_w  = (const float*)d_in[8];
  const float* lin_b  = (const float*)d_in[9];
  float* out = (float*)d_out;

  const int N = in_sizes[0] / DFEAT;    // 20000
  const int E = in_sizes[1] / 2;        // 320000

  char* p = (char*)d_ws;
  u16*   A       = (u16*)p;    p += (size_t)N * KDIM * 2;
  float* H       = (float*)p;  p += (size_t)N * DFEAT * 4;
  u16*   Wt      = (u16*)p;    p += (size_t)NLAYER * DFEAT * KDIM * 2;
  int*   row_ptr = (int*)p;    p += ((size_t)(N + 1) * 4 + 15) / 16 * 16;
  int*   cursor  = (int*)p;    p += (size_t)N * 4;                 // doubles as counts
  int*   csr_src = (int*)p;    p += (size_t)E * 4;
  float* sums    = (float*)p;  p += (size_t)NLAYER * 2 * DFEAT * 4;  // per-layer
  float* ss      = (float*)p;  p += 2 * DFEAT * 4;
  float* pooled  = (float*)p;  p += (size_t)NGRAPH * DFEAT * 4;

  // ---- zero atomics targets once ----
  hipMemsetAsync(cursor, 0, (size_t)N * 4, stream);
  hipMemsetAsync(sums, 0, (size_t)NLAYER * 2 * DFEAT * 4, stream);

  // ---- CSR build ----
  hist_kernel<<<(E + 255) / 256, 256, 0, stream>>>(ei, cursor, E);
  scan_kernel<<<1, 1024, 0, stream>>>(cursor, row_ptr, N);
  hipMemcpyAsync(cursor, row_ptr, (size_t)N * 4, hipMemcpyDeviceToDevice, stream);
  scatter_kernel<<<(E + 255) / 256, 256, 0, stream>>>(ei, cursor, csr_src, E);

  // ---- weight + input conversion ----
  wconv_kernel<<<(NLAYER * DFEAT * KDIM) / 256, 256, 0, stream>>>(W_rel, W_root, Wt);
  xconv_kernel<<<(N * 128 + 255) / 256, 256, 0, stream>>>(x, A, N);

  const int gemm_gx = (N + BM - 1) / BM;
  dim3 gemm_grid(gemm_gx, DFEAT / BN, 1);

  for (int l = 0; l < NLAYER; ++l) {
    float* sums_l = sums + (size_t)l * 2 * DFEAT;
    gather_kernel<<<(N + 3) / 4, 256, 0, stream>>>(A, row_ptr, csr_src, N);
    gemm_kernel<<<gemm_grid, 256, 0, stream>>>(A, Wt + (size_t)l * DFEAT * KDIM,
                                               b_rel + (size_t)l * DFEAT, H, sums_l, N);
    finalize_kernel<<<1, DFEAT, 0, stream>>>(sums_l, gamma + (size_t)l * DFEAT,
                                             beta + (size_t)l * DFEAT, ss, 1.0f / (float)N);
    norm_kernel<<<(N * 128 + 255) / 256, 256, 0, stream>>>(H, ss, A, N);
  }

  pool_kernel<<<NGRAPH, 1024, 0, stream>>>(A, batch, pooled, N);
  final_kernel<<<NGRAPH, 64, 0, stream>>>(pooled, lin_w, lin_b, out);
}